// Round 1
// baseline (9351.115 us; speedup 1.0000x reference)
//
#include <hip/hip_runtime.h>
#include <math.h>

constexpr int NB = 512;     // batch
constexpr int NS = 140;     // encoder steps
constexpr int NH = 512;     // hidden
constexpr int NE = 256;     // embedding
constexpr int NV = 1000;    // vocab
constexpr int NT = 21;      // decode steps
constexpr int ND = 7;       // days
constexpr int DL = 20;      // steps per day
constexpr int SOS = 2;
constexpr int LSTR = NT + 1;  // label row stride = 22

// ---------------------------------------------------------------------------
// Generic 64x64-tile fp32 GEMM, 256 threads, 4x4 micro-tile per thread.
// AMODE: 0 = plain A[row*lda+k]; 1 = embedding gather (A0=emb, row->dec idx);
//        2 = concat (k<512 from A0=h_new, else A1=ctx; both [NB,512])
// BTRANS: 0 = B[k*ldb+n]; 1 = B[n*ldb+k]
// EPI: 0 = none; 1 = +bias[n]; 2 = tanh
// M is always 512 (full tiles); N may be ragged (bounds-checked).
// ---------------------------------------------------------------------------
template<int AMODE, int BTRANS, int EPI>
__global__ __launch_bounds__(256) void gemm64(
    const float* __restrict__ A0, const float* __restrict__ A1,
    const float* __restrict__ Bm, const float* __restrict__ bias,
    float* __restrict__ C, int N, int K,
    int lda, int ldb, int ldc,
    const int* __restrict__ label, int t)
{
  __shared__ float As[64][17];
  __shared__ float Bs[16][65];
  const int tid = threadIdx.x;
  const int tx = tid & 15, ty = tid >> 4;
  const int rowBase = blockIdx.y * 64;
  const int colBase = blockIdx.x * 64;

  float acc[4][4];
#pragma unroll
  for (int i = 0; i < 4; ++i)
#pragma unroll
    for (int j = 0; j < 4; ++j) acc[i][j] = 0.f;

  for (int k0 = 0; k0 < K; k0 += 16) {
    // ---- load A tile: 64 rows x 16 k
#pragma unroll
    for (int p = 0; p < 4; ++p) {
      const int m = (tid >> 4) + p * 16;
      const int kk = tid & 15;
      const int row = rowBase + m;
      const int kg = k0 + kk;
      float v;
      if (AMODE == 0) {
        v = A0[(size_t)row * lda + kg];
      } else if (AMODE == 1) {
        const int dec = (t == 0) ? SOS : label[row * LSTR + (t - 1)];
        v = A0[(size_t)dec * lda + kg];
      } else {
        v = (kg < NH) ? A0[(size_t)row * NH + kg]
                      : A1[(size_t)row * NH + (kg - NH)];
      }
      As[m][kk] = v;
    }
    // ---- load B tile: 16 k x 64 n
    if (BTRANS == 0) {
#pragma unroll
      for (int p = 0; p < 4; ++p) {
        const int n = tid & 63;
        const int kk = (tid >> 6) + p * 4;
        const int col = colBase + n;
        Bs[kk][n] = (col < N) ? Bm[(size_t)(k0 + kk) * ldb + col] : 0.f;
      }
    } else {
#pragma unroll
      for (int p = 0; p < 4; ++p) {
        const int kk = tid & 15;
        const int n = (tid >> 4) + p * 16;
        const int col = colBase + n;
        Bs[kk][n] = (col < N) ? Bm[(size_t)col * ldb + (k0 + kk)] : 0.f;
      }
    }
    __syncthreads();
#pragma unroll
    for (int kk = 0; kk < 16; ++kk) {
      float a[4], b[4];
#pragma unroll
      for (int i = 0; i < 4; ++i) a[i] = As[ty + 16 * i][kk];
#pragma unroll
      for (int j = 0; j < 4; ++j) b[j] = Bs[kk][tx + 16 * j];
#pragma unroll
      for (int i = 0; i < 4; ++i)
#pragma unroll
        for (int j = 0; j < 4; ++j) acc[i][j] += a[i] * b[j];
    }
    __syncthreads();
  }

#pragma unroll
  for (int i = 0; i < 4; ++i) {
    const int row = rowBase + ty + 16 * i;
#pragma unroll
    for (int j = 0; j < 4; ++j) {
      const int col = colBase + tx + 16 * j;
      if (col < N) {
        float v = acc[i][j];
        if (EPI == 1) v += bias[col];
        if (EPI == 2) v = tanhf(v);
        C[(size_t)row * ldc + col] = v;
      }
    }
  }
}

// ---------------------------------------------------------------------------
// Day attention: one block per (b,d). Stage enc[b,d,:,:] (20x512) in LDS,
// sc[s] = enc[s,:].u[b,:], masked softmax over 20, week[b,d,:] = wd.enc.
// ---------------------------------------------------------------------------
__global__ __launch_bounds__(256) void day_attn(
    const float* __restrict__ enc, const float* __restrict__ u,
    const int* __restrict__ numpairs, float* __restrict__ week)
{
  const int b = blockIdx.x / ND;
  const int d = blockIdx.x % ND;
  __shared__ float encs[DL * NH];   // 40 KB
  __shared__ float uS[NH];
  __shared__ float scS[DL];
  __shared__ float wdS[DL];
  const int tid = threadIdx.x;

  const float* ep = enc + ((size_t)b * NS + (size_t)d * DL) * NH;
  for (int i = tid; i < DL * NH / 4; i += 256)
    ((float4*)encs)[i] = ((const float4*)ep)[i];
  for (int i = tid; i < NH / 4; i += 256)
    ((float4*)uS)[i] = ((const float4*)(u + (size_t)b * NH))[i];
  __syncthreads();

  const int wave = tid >> 6, lane = tid & 63;
#pragma unroll
  for (int si = 0; si < 5; ++si) {
    const int s = wave * 5 + si;
    float p = 0.f;
    for (int h = lane; h < NH; h += 64) p += encs[s * NH + h] * uS[h];
#pragma unroll
    for (int off = 32; off; off >>= 1) p += __shfl_down(p, off);
    if (lane == 0) scS[s] = p;
  }
  __syncthreads();

  if (tid == 0) {
    float sc[DL];
    float mx = -1e30f;
    for (int s = 0; s < DL; ++s) {
      float v = (numpairs[b * NS + d * DL + s] != 0) ? scS[s] : -1e9f;
      sc[s] = v;
      mx = fmaxf(mx, v);
    }
    float sum = 0.f;
    for (int s = 0; s < DL; ++s) { float e = expf(sc[s] - mx); sc[s] = e; sum += e; }
    const float inv = 1.f / sum;
    for (int s = 0; s < DL; ++s) wdS[s] = sc[s] * inv;
  }
  __syncthreads();

  for (int h = tid; h < NH; h += 256) {
    float a = 0.f;
#pragma unroll
    for (int s = 0; s < DL; ++s) a += wdS[s] * encs[s * NH + h];
    week[((size_t)b * ND + d) * NH + h] = a;
  }
}

// ---------------------------------------------------------------------------
// GRU gates: h_new = (1-z)*n + z*h   (PyTorch r,z,n layout; biases folded here)
// ---------------------------------------------------------------------------
__global__ __launch_bounds__(256) void gru_gates(
    const float* __restrict__ gi, const float* __restrict__ gh,
    const float* __restrict__ b_ih, const float* __restrict__ b_hh,
    const float* __restrict__ h, float* __restrict__ hn)
{
  const int idx = blockIdx.x * 256 + threadIdx.x;  // b*NH + j
  const int b = idx >> 9, j = idx & (NH - 1);
  const float* gib = gi + (size_t)b * 3 * NH;
  const float* ghb = gh + (size_t)b * 3 * NH;
  const float ir = gib[j] + b_ih[j];
  const float iz = gib[NH + j] + b_ih[NH + j];
  const float in_ = gib[2 * NH + j] + b_ih[2 * NH + j];
  const float hr = ghb[j] + b_hh[j];
  const float hz = ghb[NH + j] + b_hh[NH + j];
  const float hn_ = ghb[2 * NH + j] + b_hh[2 * NH + j];
  const float r = 1.f / (1.f + expf(-(ir + hr)));
  const float z = 1.f / (1.f + expf(-(iz + hz)));
  const float n = tanhf(in_ + r * hn_);
  hn[idx] = (1.f - z) * n + z * h[idx];
}

// ---------------------------------------------------------------------------
// Week attention: one block per b. scores[d] = week[b,d,:].v[b,:], softmax(7),
// ctx[b,:] = sum_d aw[d]*week[b,d,:]
// ---------------------------------------------------------------------------
__global__ __launch_bounds__(256) void week_attn(
    const float* __restrict__ v, const float* __restrict__ week,
    float* __restrict__ ctx)
{
  const int b = blockIdx.x;
  const int tid = threadIdx.x;
  const int h0 = tid, h1 = tid + 256;
  const float v0 = v[(size_t)b * NH + h0];
  const float v1 = v[(size_t)b * NH + h1];
  const float* wk = week + (size_t)b * ND * NH;

  __shared__ float red[ND][5];
  __shared__ float awS[ND];
  const int wave = tid >> 6, lane = tid & 63;
#pragma unroll
  for (int d = 0; d < ND; ++d) {
    float p = v0 * wk[d * NH + h0] + v1 * wk[d * NH + h1];
#pragma unroll
    for (int off = 32; off; off >>= 1) p += __shfl_down(p, off);
    if (lane == 0) red[d][wave] = p;
  }
  __syncthreads();
  if (tid == 0) {
    float s[ND];
    float mx = -1e30f;
    for (int d = 0; d < ND; ++d) {
      s[d] = red[d][0] + red[d][1] + red[d][2] + red[d][3];
      mx = fmaxf(mx, s[d]);
    }
    float sum = 0.f;
    for (int d = 0; d < ND; ++d) { float e = expf(s[d] - mx); s[d] = e; sum += e; }
    const float inv = 1.f / sum;
    for (int d = 0; d < ND; ++d) awS[d] = s[d] * inv;
  }
  __syncthreads();
  float c0 = 0.f, c1 = 0.f;
#pragma unroll
  for (int d = 0; d < ND; ++d) {
    const float a = awS[d];
    c0 += a * wk[d * NH + h0];
    c1 += a * wk[d * NH + h1];
  }
  ctx[(size_t)b * NH + h0] = c0;
  ctx[(size_t)b * NH + h1] = c1;
}

// ---------------------------------------------------------------------------
// In-place log_softmax over out[b, t, :] (1000 elems per row)
// ---------------------------------------------------------------------------
__global__ __launch_bounds__(256) void log_softmax_rows(float* __restrict__ out, int t)
{
  const int b = blockIdx.x;
  float* row = out + (size_t)b * NT * NV + (size_t)t * NV;
  const int tid = threadIdx.x;
  const int wave = tid >> 6, lane = tid & 63;
  __shared__ float redm[4];
  __shared__ float reds[4];

  float mx = -1e30f;
  for (int v = tid; v < NV; v += 256) mx = fmaxf(mx, row[v]);
#pragma unroll
  for (int off = 32; off; off >>= 1) mx = fmaxf(mx, __shfl_down(mx, off));
  if (lane == 0) redm[wave] = mx;
  __syncthreads();
  if (tid == 0) redm[0] = fmaxf(fmaxf(redm[0], redm[1]), fmaxf(redm[2], redm[3]));
  __syncthreads();
  mx = redm[0];

  float s = 0.f;
  for (int v = tid; v < NV; v += 256) s += expf(row[v] - mx);
#pragma unroll
  for (int off = 32; off; off >>= 1) s += __shfl_down(s, off);
  if (lane == 0) reds[wave] = s;
  __syncthreads();
  if (tid == 0) reds[0] = reds[0] + reds[1] + reds[2] + reds[3];
  __syncthreads();
  const float lse = mx + logf(reds[0]);
  for (int v = tid; v < NV; v += 256) row[v] -= lse;
}

// last_in = label[:, NT-1] as float
__global__ void write_last(const int* __restrict__ label, float* __restrict__ out2)
{
  const int b = blockIdx.x * 256 + threadIdx.x;
  if (b < NB) out2[b] = (float)label[b * LSTR + (NT - 1)];
}

// ---------------------------------------------------------------------------
extern "C" void kernel_launch(void* const* d_in, const int* in_sizes, int n_in,
                              void* d_out, int out_size, void* d_ws, size_t ws_size,
                              hipStream_t stream)
{
  const float* enc_h  = (const float*)d_in[0];   // (1,B,H)
  const float* enc    = (const float*)d_in[1];   // (B,S,H)
  const int*   label  = (const int*)d_in[2];     // (B,22)
  const int*   numprs = (const int*)d_in[3];     // (B,S)
  const float* emb    = (const float*)d_in[4];   // (V,E)
  const float* W_ih   = (const float*)d_in[5];   // (3H,E)
  const float* W_hh   = (const float*)d_in[6];   // (3H,H)
  const float* b_ih   = (const float*)d_in[7];
  const float* b_hh   = (const float*)d_in[8];
  const float* Wa     = (const float*)d_in[9];   // (H,H)
  const float* wa_W   = (const float*)d_in[10];  // (H,2H)
  const float* fc_W   = (const float*)d_in[11];  // (V,H)
  const float* fc_b   = (const float*)d_in[12];

  float* out  = (float*)d_out;                    // [B,T,V] then [B] last_in
  float* ws   = (float*)d_ws;

  // workspace layout (floats)
  float* hA   = ws;                       // B*H
  float* hB   = hA + NB * NH;             // B*H
  float* u    = hB + NB * NH;             // B*H
  float* gi   = u + NB * NH;              // B*3H
  float* gh   = gi + NB * 3 * NH;         // B*3H
  float* week = gh + NB * 3 * NH;         // B*7*H
  float* vv   = week + NB * ND * NH;      // B*H
  float* ctx  = vv + NB * NH;             // B*H
  float* aa   = ctx + NB * NH;            // B*H

  // h0 = encoder_hidden[0]
  hipMemcpyAsync(hA, enc_h, (size_t)NB * NH * sizeof(float),
                 hipMemcpyDeviceToDevice, stream);

  const dim3 blk(256);
  for (int t = 0; t < NT; ++t) {
    float* hcur = (t & 1) ? hB : hA;
    float* hnxt = (t & 1) ? hA : hB;

    // u = h @ Wa     [512,512,K=512]
    gemm64<0, 0, 0><<<dim3(8, 8), blk, 0, stream>>>(
        hcur, nullptr, Wa, nullptr, u, NH, NH, NH, NH, NH, nullptr, 0);
    // day attention -> week [B,7,H]
    day_attn<<<dim3(NB * ND), blk, 0, stream>>>(enc, u, numprs, week);
    // gi = emb[dec] @ W_ih^T   [512,1536,K=256]
    gemm64<1, 1, 0><<<dim3(24, 8), blk, 0, stream>>>(
        emb, nullptr, W_ih, nullptr, gi, 3 * NH, NE, NE, NE, 3 * NH, label, t);
    // gh = h @ W_hh^T          [512,1536,K=512]
    gemm64<0, 1, 0><<<dim3(24, 8), blk, 0, stream>>>(
        hcur, nullptr, W_hh, nullptr, gh, 3 * NH, NH, NH, NH, 3 * NH, nullptr, 0);
    // gates -> h_new
    gru_gates<<<dim3(NB * NH / 256), blk, 0, stream>>>(gi, gh, b_ih, b_hh, hcur, hnxt);
    // v = h_new @ Wa           [512,512,K=512]
    gemm64<0, 0, 0><<<dim3(8, 8), blk, 0, stream>>>(
        hnxt, nullptr, Wa, nullptr, vv, NH, NH, NH, NH, NH, nullptr, 0);
    // week attention -> ctx
    week_attn<<<dim3(NB), blk, 0, stream>>>(vv, week, ctx);
    // a = tanh([h_new,ctx] @ wa_W^T)   [512,512,K=1024]
    gemm64<2, 1, 2><<<dim3(8, 8), blk, 0, stream>>>(
        hnxt, ctx, wa_W, nullptr, aa, NH, 2 * NH, NH, 2 * NH, NH, nullptr, 0);
    // logits = a @ fc_W^T + fc_b -> out[:, t, :]   [512,1000,K=512]
    gemm64<0, 1, 1><<<dim3(16, 8), blk, 0, stream>>>(
        aa, nullptr, fc_W, fc_b, out + (size_t)t * NV, NV, NH, NH, NH, NT * NV,
        nullptr, 0);
    // in-place log_softmax on the rows just written
    log_softmax_rows<<<dim3(NB), blk, 0, stream>>>(out, t);
  }

  write_last<<<dim3(2), blk, 0, stream>>>(label, out + (size_t)NB * NT * NV);
}

// Round 2
// 2103.118 us; speedup vs baseline: 4.4463x; 4.4463x over previous
//
#include <hip/hip_runtime.h>
#include <math.h>

typedef __attribute__((ext_vector_type(8))) short bf16x8;
typedef __attribute__((ext_vector_type(4))) float f32x4;

constexpr int NB = 512;     // batch
constexpr int NS = 140;     // encoder steps
constexpr int NH = 512;     // hidden
constexpr int NE = 256;     // embedding
constexpr int NV = 1000;    // vocab
constexpr int NT = 21;      // decode steps
constexpr int ND = 7;       // days
constexpr int DL = 20;      // steps per day
constexpr int SOS = 2;
constexpr int LSTR = NT + 1;  // label row stride = 22

__device__ __forceinline__ unsigned short f2bf(float f) {
  union { float f; unsigned u; } v; v.f = f;
  unsigned r = v.u + 0x7fffu + ((v.u >> 16) & 1u);
  return (unsigned short)(r >> 16);
}
__device__ __forceinline__ float bf2f(unsigned short h) {
  union { unsigned u; float f; } v; v.u = ((unsigned)h) << 16;
  return v.f;
}

// ---------------------------------------------------------------------------
// bf16 MFMA GEMM: C[M x N] = A[M x K] * Bt[N x K]^T  (Bt is n-major bf16)
// 64x64 tile / block, 256 threads (4 waves), K-chunk 32, register prefetch.
// AMODE: 0 = A0[row*lda+k] fp32; 1 = emb gather (row -> (t,b), dec index);
//        2 = concat: k<512 from A0[row*512+k], else A1[row*512+k-512]
// EPI: 0 none; 1 +bias[n]; 2 tanh.  OUT16: write bf16 to C16 instead of C.
// M must be a multiple of 64; N ragged ok.
// ---------------------------------------------------------------------------
template<int AMODE, int EPI, int OUT16>
__global__ __launch_bounds__(256) void gemm_bf16(
    const float* __restrict__ A0, const float* __restrict__ A1,
    const unsigned short* __restrict__ Bt, const float* __restrict__ bias,
    float* __restrict__ C, unsigned short* __restrict__ C16,
    int N, int K, int lda, int ldc,
    const int* __restrict__ label, int tbase)
{
  __shared__ unsigned short As[64 * 40];   // row-major, stride 40 (pad)
  __shared__ unsigned short Bs[64 * 40];   // n-major, stride 40
  const int tid = threadIdx.x;
  const int rowBase = blockIdx.y * 64, colBase = blockIdx.x * 64;
  const int wave = tid >> 6, lane = tid & 63, quad = lane >> 4, l15 = lane & 15;
  const int rw = (wave & 1) * 32, cw = (wave >> 1) * 32;

  f32x4 acc[2][2];
#pragma unroll
  for (int i = 0; i < 2; ++i)
#pragma unroll
    for (int j = 0; j < 2; ++j)
#pragma unroll
      for (int r = 0; r < 4; ++r) acc[i][j][r] = 0.f;

  const int ar = tid >> 2;          // 0..63 (row within tile)
  const int kq = (tid & 3) * 8;     // 0,8,16,24 (k within chunk)
  const int aRowG = rowBase + ar;
  const float* aptr = nullptr;
  if (AMODE == 1) {
    const int t = (aRowG >> 9) + tbase;
    const int b = aRowG & 511;
    const int dec = (t == 0) ? SOS : label[b * LSTR + (t - 1)];
    aptr = A0 + (size_t)dec * lda + kq;
  } else if (AMODE == 0) {
    aptr = A0 + (size_t)aRowG * lda + kq;
  }
  const int bn = colBase + ar;
  const unsigned short* bptr = Bt + (size_t)bn * K + kq;
  const bool bvalid = bn < N;
  unsigned short* asd = &As[ar * 40 + kq];
  unsigned short* bsd = &Bs[ar * 40 + kq];

  float4 x0, x1;
  uint4 bv = make_uint4(0, 0, 0, 0);
  // prologue load, chunk 0
  if (AMODE == 2) {
    const float* ap = (kq < NH) ? (A0 + (size_t)aRowG * NH + kq)
                                : (A1 + (size_t)aRowG * NH + kq - NH);
    x0 = *(const float4*)ap; x1 = *(const float4*)(ap + 4);
  } else {
    x0 = *(const float4*)(aptr); x1 = *(const float4*)(aptr + 4);
  }
  if (bvalid) bv = *(const uint4*)(bptr);

  for (int k0 = 0; k0 < K; k0 += 32) {
    uint4 av;
    av.x = (unsigned)f2bf(x0.x) | ((unsigned)f2bf(x0.y) << 16);
    av.y = (unsigned)f2bf(x0.z) | ((unsigned)f2bf(x0.w) << 16);
    av.z = (unsigned)f2bf(x1.x) | ((unsigned)f2bf(x1.y) << 16);
    av.w = (unsigned)f2bf(x1.z) | ((unsigned)f2bf(x1.w) << 16);
    *(uint4*)asd = av;
    *(uint4*)bsd = bv;
    __syncthreads();

    // prefetch next chunk while MFMAs run
    const int kn = k0 + 32;
    if (kn < K) {
      if (AMODE == 2) {
        const float* ap = (kn + kq < NH) ? (A0 + (size_t)aRowG * NH + kn + kq)
                                         : (A1 + (size_t)aRowG * NH + kn + kq - NH);
        x0 = *(const float4*)ap; x1 = *(const float4*)(ap + 4);
      } else {
        x0 = *(const float4*)(aptr + kn); x1 = *(const float4*)(aptr + kn + 4);
      }
      if (bvalid) bv = *(const uint4*)(bptr + kn);
    }

    const bf16x8 af0 = *(const bf16x8*)&As[(rw + l15) * 40 + quad * 8];
    const bf16x8 af1 = *(const bf16x8*)&As[(rw + 16 + l15) * 40 + quad * 8];
    const bf16x8 bf0 = *(const bf16x8*)&Bs[(cw + l15) * 40 + quad * 8];
    const bf16x8 bf1 = *(const bf16x8*)&Bs[(cw + 16 + l15) * 40 + quad * 8];
    acc[0][0] = __builtin_amdgcn_mfma_f32_16x16x32_bf16(af0, bf0, acc[0][0], 0, 0, 0);
    acc[0][1] = __builtin_amdgcn_mfma_f32_16x16x32_bf16(af0, bf1, acc[0][1], 0, 0, 0);
    acc[1][0] = __builtin_amdgcn_mfma_f32_16x16x32_bf16(af1, bf0, acc[1][0], 0, 0, 0);
    acc[1][1] = __builtin_amdgcn_mfma_f32_16x16x32_bf16(af1, bf1, acc[1][1], 0, 0, 0);
    __syncthreads();
  }

#pragma unroll
  for (int i = 0; i < 2; ++i) {
    const int grow = rowBase + rw + 16 * i + quad * 4;
#pragma unroll
    for (int j = 0; j < 2; ++j) {
      const int gcol = colBase + cw + 16 * j + l15;
      if (gcol < N) {
#pragma unroll
        for (int r = 0; r < 4; ++r) {
          float vo = acc[i][j][r];
          if (EPI == 1) vo += bias[gcol];
          if (EPI == 2) vo = tanhf(vo);
          if (OUT16) C16[(size_t)(grow + r) * ldc + gcol] = f2bf(vo);
          else       C[(size_t)(grow + r) * ldc + gcol] = vo;
        }
      }
    }
  }
}

// ---------------------------------------------------------------------------
// Day attention, bf16 enc in LDS. One block per (b,d).
// sc[s] = enc[b,d,s,:].u[b,:]; masked softmax(20); week[b,d,:] = wd.enc
// u read from ug (stride 2048, cols 0..511).
// ---------------------------------------------------------------------------
template<int ENC16>
__global__ __launch_bounds__(256) void day_attn(
    const float* __restrict__ encf, const unsigned short* __restrict__ ench,
    const float* __restrict__ ug, const int* __restrict__ numpairs,
    float* __restrict__ week)
{
  const int b = blockIdx.x / ND;
  const int d = blockIdx.x % ND;
  __shared__ unsigned short encs[DL * NH];   // 20 KB
  __shared__ float uS[NH];
  __shared__ float scS[DL], wdS[DL];
  const int tid = threadIdx.x;

  if (ENC16) {
    const uint4* ep = (const uint4*)(ench + ((size_t)b * NS + d * DL) * NH);
    uint4* dst = (uint4*)encs;
    for (int i = tid; i < DL * NH / 8; i += 256) dst[i] = ep[i];
  } else {
    const float* ep = encf + ((size_t)b * NS + d * DL) * NH;
    uint4* dst = (uint4*)encs;
    for (int i = tid; i < DL * NH / 8; i += 256) {
      float4 y0 = *(const float4*)(ep + i * 8);
      float4 y1 = *(const float4*)(ep + i * 8 + 4);
      uint4 pv;
      pv.x = (unsigned)f2bf(y0.x) | ((unsigned)f2bf(y0.y) << 16);
      pv.y = (unsigned)f2bf(y0.z) | ((unsigned)f2bf(y0.w) << 16);
      pv.z = (unsigned)f2bf(y1.x) | ((unsigned)f2bf(y1.y) << 16);
      pv.w = (unsigned)f2bf(y1.z) | ((unsigned)f2bf(y1.w) << 16);
      dst[i] = pv;
    }
  }
  if (tid < NH / 4)
    ((float4*)uS)[tid] = ((const float4*)(ug + (size_t)b * 2048))[tid];
  __syncthreads();

  const int wave = tid >> 6, lane = tid & 63;
  float u8[8];
  {
    float4 a = *(const float4*)(uS + lane * 8);
    float4 c = *(const float4*)(uS + lane * 8 + 4);
    u8[0] = a.x; u8[1] = a.y; u8[2] = a.z; u8[3] = a.w;
    u8[4] = c.x; u8[5] = c.y; u8[6] = c.z; u8[7] = c.w;
  }
#pragma unroll
  for (int si = 0; si < 5; ++si) {
    const int s = wave * 5 + si;
    const bf16x8 ev = *(const bf16x8*)&encs[s * NH + lane * 8];
    float p = 0.f;
#pragma unroll
    for (int j = 0; j < 8; ++j) p += bf2f((unsigned short)ev[j]) * u8[j];
#pragma unroll
    for (int off = 32; off; off >>= 1) p += __shfl_down(p, off);
    if (lane == 0) scS[s] = p;
  }
  __syncthreads();

  if (tid == 0) {
    float sc[DL];
    float mx = -1e30f;
    for (int s = 0; s < DL; ++s) {
      float v = (numpairs[b * NS + d * DL + s] != 0) ? scS[s] : -1e9f;
      sc[s] = v; mx = fmaxf(mx, v);
    }
    float sum = 0.f;
    for (int s = 0; s < DL; ++s) { float e = expf(sc[s] - mx); sc[s] = e; sum += e; }
    const float inv = 1.f / sum;
    for (int s = 0; s < DL; ++s) wdS[s] = sc[s] * inv;
  }
  __syncthreads();

  float a0 = 0.f, a1 = 0.f;
#pragma unroll
  for (int s = 0; s < DL; ++s) {
    const float w = wdS[s];
    const unsigned pv = *(const unsigned*)&encs[s * NH + tid * 2];
    a0 += w * bf2f((unsigned short)(pv & 0xffffu));
    a1 += w * bf2f((unsigned short)(pv >> 16));
  }
  float2 r; r.x = a0; r.y = a1;
  *(float2*)(week + ((size_t)b * ND + d) * NH + tid * 2) = r;
}

// ---------------------------------------------------------------------------
// GRU gates: gi from bf16 precompute, gh from ug cols 512..2047.
// ---------------------------------------------------------------------------
__global__ __launch_bounds__(256) void gru_gates(
    const unsigned short* __restrict__ git, const float* __restrict__ ug,
    const float* __restrict__ b_ih, const float* __restrict__ b_hh,
    const float* __restrict__ h, float* __restrict__ hn)
{
  const int idx = blockIdx.x * 256 + threadIdx.x;  // b*NH + j
  const int b = idx >> 9, j = idx & (NH - 1);
  const unsigned short* gib = git + (size_t)b * 1536;
  const float* ghb = ug + (size_t)b * 2048 + NH;
  const float ir  = bf2f(gib[j]) + b_ih[j];
  const float iz  = bf2f(gib[NH + j]) + b_ih[NH + j];
  const float in_ = bf2f(gib[2 * NH + j]) + b_ih[2 * NH + j];
  const float hr  = ghb[j] + b_hh[j];
  const float hz  = ghb[NH + j] + b_hh[NH + j];
  const float hn_ = ghb[2 * NH + j] + b_hh[2 * NH + j];
  const float rg = 1.f / (1.f + expf(-(ir + hr)));
  const float zg = 1.f / (1.f + expf(-(iz + hz)));
  const float ng = tanhf(in_ + rg * hn_);
  hn[idx] = (1.f - zg) * ng + zg * h[idx];
}

// ---------------------------------------------------------------------------
// Week attention: one block per b.
// ---------------------------------------------------------------------------
__global__ __launch_bounds__(256) void week_attn(
    const float* __restrict__ v, const float* __restrict__ week,
    float* __restrict__ ctx)
{
  const int b = blockIdx.x;
  const int tid = threadIdx.x;
  const int h0 = tid, h1 = tid + 256;
  const float v0 = v[(size_t)b * NH + h0];
  const float v1 = v[(size_t)b * NH + h1];
  const float* wk = week + (size_t)b * ND * NH;

  __shared__ float red[ND][5];
  __shared__ float awS[ND];
  const int wave = tid >> 6, lane = tid & 63;
#pragma unroll
  for (int d = 0; d < ND; ++d) {
    float p = v0 * wk[d * NH + h0] + v1 * wk[d * NH + h1];
#pragma unroll
    for (int off = 32; off; off >>= 1) p += __shfl_down(p, off);
    if (lane == 0) red[d][wave] = p;
  }
  __syncthreads();
  if (tid == 0) {
    float s[ND];
    float mx = -1e30f;
    for (int d = 0; d < ND; ++d) {
      s[d] = red[d][0] + red[d][1] + red[d][2] + red[d][3];
      mx = fmaxf(mx, s[d]);
    }
    float sum = 0.f;
    for (int d = 0; d < ND; ++d) { float e = expf(s[d] - mx); s[d] = e; sum += e; }
    const float inv = 1.f / sum;
    for (int d = 0; d < ND; ++d) awS[d] = s[d] * inv;
  }
  __syncthreads();
  float c0 = 0.f, c1 = 0.f;
#pragma unroll
  for (int d = 0; d < ND; ++d) {
    const float a = awS[d];
    c0 += a * wk[d * NH + h0];
    c1 += a * wk[d * NH + h1];
  }
  ctx[(size_t)b * NH + h0] = c0;
  ctx[(size_t)b * NH + h1] = c1;
}

// ---------------------------------------------------------------------------
// In-place log_softmax over out[b, t, :]
// ---------------------------------------------------------------------------
__global__ __launch_bounds__(256) void log_softmax_rows(float* __restrict__ out, int t)
{
  const int b = blockIdx.x;
  float* row = out + (size_t)b * NT * NV + (size_t)t * NV;
  const int tid = threadIdx.x;
  const int wave = tid >> 6, lane = tid & 63;
  __shared__ float redm[4];
  __shared__ float reds[4];

  float mx = -1e30f;
  for (int v = tid; v < NV; v += 256) mx = fmaxf(mx, row[v]);
#pragma unroll
  for (int off = 32; off; off >>= 1) mx = fmaxf(mx, __shfl_down(mx, off));
  if (lane == 0) redm[wave] = mx;
  __syncthreads();
  if (tid == 0) redm[0] = fmaxf(fmaxf(redm[0], redm[1]), fmaxf(redm[2], redm[3]));
  __syncthreads();
  mx = redm[0];

  float s = 0.f;
  for (int v = tid; v < NV; v += 256) s += expf(row[v] - mx);
#pragma unroll
  for (int off = 32; off; off >>= 1) s += __shfl_down(s, off);
  if (lane == 0) reds[wave] = s;
  __syncthreads();
  if (tid == 0) reds[0] = reds[0] + reds[1] + reds[2] + reds[3];
  __syncthreads();
  const float lse = mx + logf(reds[0]);
  for (int v = tid; v < NV; v += 256) row[v] -= lse;
}

__global__ void write_last(const int* __restrict__ label, float* __restrict__ out2)
{
  const int b = blockIdx.x * 256 + threadIdx.x;
  if (b < NB) out2[b] = (float)label[b * LSTR + (NT - 1)];
}

// ---------------------------------------------------------------------------
// Weight packing (once per call)
// ---------------------------------------------------------------------------
__global__ __launch_bounds__(256) void pack_w1(
    const float* __restrict__ Wa, const float* __restrict__ Whh,
    unsigned short* __restrict__ W1t)
{
  const int idx = blockIdx.x * 256 + threadIdx.x;   // over 2048*512
  const int n = idx >> 9, k = idx & 511;
  const float v = (n < NH) ? Wa[k * NH + n] : Whh[(size_t)(n - NH) * NH + k];
  W1t[idx] = f2bf(v);
}

__global__ __launch_bounds__(256) void cast4(
    const float4* __restrict__ in, ushort4* __restrict__ out, int n4)
{
  const int i = blockIdx.x * 256 + threadIdx.x;
  if (i < n4) {
    const float4 x = in[i];
    ushort4 r;
    r.x = f2bf(x.x); r.y = f2bf(x.y); r.z = f2bf(x.z); r.w = f2bf(x.w);
    out[i] = r;
  }
}

// ---------------------------------------------------------------------------
extern "C" void kernel_launch(void* const* d_in, const int* in_sizes, int n_in,
                              void* d_out, int out_size, void* d_ws, size_t ws_size,
                              hipStream_t stream)
{
  const float* enc_h  = (const float*)d_in[0];
  const float* enc    = (const float*)d_in[1];
  const int*   label  = (const int*)d_in[2];
  const int*   numprs = (const int*)d_in[3];
  const float* emb    = (const float*)d_in[4];
  const float* W_ih   = (const float*)d_in[5];
  const float* W_hh   = (const float*)d_in[6];
  const float* b_ih   = (const float*)d_in[7];
  const float* b_hh   = (const float*)d_in[8];
  const float* Wa     = (const float*)d_in[9];
  const float* wa_W   = (const float*)d_in[10];
  const float* fc_W   = (const float*)d_in[11];
  const float* fc_b   = (const float*)d_in[12];
  float* out = (float*)d_out;

  // ---- workspace carve ----
  float* f = (float*)d_ws;
  float* hA   = f; f += NB * NH;
  float* hB   = f; f += NB * NH;
  float* ug   = f; f += NB * 2048;        // u (cols 0..511) | gh (512..2047)
  float* vv   = f; f += NB * NH;
  float* week = f; f += NB * ND * NH;
  float* ctx  = f; f += NB * NH;
  float* aa   = f; f += NB * NH;
  unsigned short* us = (unsigned short*)f;
  unsigned short* W1t  = us; us += 2048 * 512;
  unsigned short* W3t  = us; us += 512 * 1024;
  unsigned short* W4t  = us; us += 1000 * 512;
  unsigned short* Wiht = us; us += 1536 * 256;
  size_t used = (size_t)((char*)us - (char*)d_ws);
  const size_t giFullElems = (size_t)NT * NB * 1536;
  const bool giFull = ws_size >= used + giFullElems * 2;
  unsigned short* Gi = us; us += giFull ? giFullElems : (size_t)NB * 1536;
  used = (size_t)((char*)us - (char*)d_ws);
  const size_t encElems = (size_t)NB * NS * NH;
  const bool useEnc16 = ws_size >= used + encElems * 2;
  unsigned short* enc16 = us;

  const dim3 blk(256);

  // h0 = encoder_hidden[0]
  hipMemcpyAsync(hA, enc_h, (size_t)NB * NH * sizeof(float),
                 hipMemcpyDeviceToDevice, stream);

  // ---- one-time packs ----
  pack_w1<<<dim3(2048 * 512 / 256), blk, 0, stream>>>(Wa, W_hh, W1t);
  cast4<<<dim3(512 * 1024 / 4 / 256), blk, 0, stream>>>(
      (const float4*)wa_W, (ushort4*)W3t, 512 * 1024 / 4);
  cast4<<<dim3((1000 * 512 / 4 + 255) / 256), blk, 0, stream>>>(
      (const float4*)fc_W, (ushort4*)W4t, 1000 * 512 / 4);
  cast4<<<dim3(1536 * 256 / 4 / 256), blk, 0, stream>>>(
      (const float4*)W_ih, (ushort4*)Wiht, 1536 * 256 / 4);
  if (useEnc16)
    cast4<<<dim3((int)((encElems / 4 + 255) / 256)), blk, 0, stream>>>(
        (const float4*)enc, (ushort4*)enc16, (int)(encElems / 4));
  if (giFull)  // all 21 steps of gi in one gather-GEMM
    gemm_bf16<1, 0, 1><<<dim3(24, 168), blk, 0, stream>>>(
        emb, nullptr, Wiht, nullptr, nullptr, Gi, 1536, 256, NE, 1536, label, 0);

  // ---- decode loop ----
  for (int t = 0; t < NT; ++t) {
    float* hcur = (t & 1) ? hB : hA;
    float* hnxt = (t & 1) ? hA : hB;

    if (!giFull)
      gemm_bf16<1, 0, 1><<<dim3(24, 8), blk, 0, stream>>>(
          emb, nullptr, Wiht, nullptr, nullptr, Gi, 1536, 256, NE, 1536, label, t);

    // [u | gh] = h @ [Wa | W_hh^T]   N=2048, K=512
    gemm_bf16<0, 0, 0><<<dim3(32, 8), blk, 0, stream>>>(
        hcur, nullptr, W1t, nullptr, ug, nullptr, 2048, 512, NH, 2048, nullptr, 0);

    if (useEnc16)
      day_attn<1><<<dim3(NB * ND), blk, 0, stream>>>(nullptr, enc16, ug, numprs, week);
    else
      day_attn<0><<<dim3(NB * ND), blk, 0, stream>>>(enc, nullptr, ug, numprs, week);

    const unsigned short* git = giFull ? (Gi + (size_t)t * NB * 1536) : Gi;
    gru_gates<<<dim3(NB * NH / 256), blk, 0, stream>>>(git, ug, b_ih, b_hh, hcur, hnxt);

    // v = h_new @ Wa   (W1t rows 0..511)
    gemm_bf16<0, 0, 0><<<dim3(8, 8), blk, 0, stream>>>(
        hnxt, nullptr, W1t, nullptr, vv, nullptr, 512, 512, NH, 512, nullptr, 0);

    week_attn<<<dim3(NB), blk, 0, stream>>>(vv, week, ctx);

    // a = tanh([h_new|ctx] @ wa_W^T)   K=1024
    gemm_bf16<2, 2, 0><<<dim3(8, 8), blk, 0, stream>>>(
        hnxt, ctx, W3t, nullptr, aa, nullptr, 512, 1024, NH, 512, nullptr, 0);

    // logits = a @ fc_W^T + fc_b -> out[:, t, :]
    gemm_bf16<0, 1, 0><<<dim3(16, 8), blk, 0, stream>>>(
        aa, nullptr, W4t, fc_b, out + (size_t)t * NV, nullptr, 1000, 512, NH,
        NT * NV, nullptr, 0);

    log_softmax_rows<<<dim3(NB), blk, 0, stream>>>(out, t);
  }

  write_last<<<dim3(2), blk, 0, stream>>>(label, out + (size_t)NB * NT * NV);
}